// Round 1
// baseline (41.866 us; speedup 1.0000x reference)
//
#include <hip/hip_runtime.h>

#define HGT 100
#define WID 152
#define HW (HGT * WID)          // 15200
#define NINST 500
#define CIN 8
#define CH 8
#define NPARAMS 169
#define PPT 4                    // pixels per thread (one float4)

// param layout per instance (169 floats):
//   w0: [0,80)   (8 x 10)
//   w1: [80,144) (8 x 8)
//   w2: [144,152)(1 x 8)
//   b0: [152,160)
//   b1: [160,168)
//   b2: [168]

__global__ __launch_bounds__(256) void dyn_mask_head(
    const float* __restrict__ feats,   // [2, 8, HW]
    const float* __restrict__ params,  // [500, 169]
    const float* __restrict__ locs,    // [500, 2]
    const float* __restrict__ soi,     // [500]
    const int*  __restrict__ im_inds,  // [500]
    float* __restrict__ out)           // [500, HW]
{
    const int n    = blockIdx.y;                                // instance
    const int quad = blockIdx.x * blockDim.x + threadIdx.x;     // float4 index
    const int p0   = quad * PPT;                                // first pixel
    if (p0 >= HW) return;

    // wave-uniform (blockIdx.y) -> scalar loads
    const int   im      = im_inds[n];
    const float lx      = locs[n * 2 + 0];
    const float ly      = locs[n * 2 + 1];
    const float inv_soi = 1.0f / soi[n];
    const float* __restrict__ P = params + n * NPARAMS;

    // quad lies entirely within one row (WID % 4 == 0)
    const int py  = p0 / WID;
    const int px0 = p0 - py * WID;
    const float rely = (ly - (float)(py * 8 + 4)) * inv_soi;

    float relx[PPT];
#pragma unroll
    for (int r = 0; r < PPT; ++r)
        relx[r] = (lx - (float)((px0 + r) * 8 + 4)) * inv_soi;

    // load 8 feature channels x 4 pixels as float4
    float f[CIN][PPT];
    const float* fb = feats + (size_t)im * CIN * HW + p0;
#pragma unroll
    for (int j = 0; j < CIN; ++j) {
        const float4 v = *reinterpret_cast<const float4*>(fb + (size_t)j * HW);
        f[j][0] = v.x; f[j][1] = v.y; f[j][2] = v.z; f[j][3] = v.w;
    }

    // ---- layer 0: 10 -> 8, relu ----
    float h0[CH][PPT];
#pragma unroll
    for (int c = 0; c < CH; ++c) {
        const float b  = P[152 + c];
        const float wx = P[c * 10 + 0];
        const float wy = P[c * 10 + 1];
        float acc[PPT];
#pragma unroll
        for (int r = 0; r < PPT; ++r) acc[r] = fmaf(wy, rely, b);
#pragma unroll
        for (int r = 0; r < PPT; ++r) acc[r] = fmaf(wx, relx[r], acc[r]);
#pragma unroll
        for (int i = 0; i < CIN; ++i) {
            const float w = P[c * 10 + 2 + i];
#pragma unroll
            for (int r = 0; r < PPT; ++r) acc[r] = fmaf(w, f[i][r], acc[r]);
        }
#pragma unroll
        for (int r = 0; r < PPT; ++r) h0[c][r] = fmaxf(acc[r], 0.0f);
    }

    // ---- layer 1: 8 -> 8, relu ----
    float h1[CH][PPT];
#pragma unroll
    for (int c = 0; c < CH; ++c) {
        const float b = P[160 + c];
        float acc[PPT];
#pragma unroll
        for (int r = 0; r < PPT; ++r) acc[r] = b;
#pragma unroll
        for (int i = 0; i < CH; ++i) {
            const float w = P[80 + c * 8 + i];
#pragma unroll
            for (int r = 0; r < PPT; ++r) acc[r] = fmaf(w, h0[i][r], acc[r]);
        }
#pragma unroll
        for (int r = 0; r < PPT; ++r) h1[c][r] = fmaxf(acc[r], 0.0f);
    }

    // ---- layer 2: 8 -> 1 ----
    const float b2 = P[168];
    float o[PPT];
#pragma unroll
    for (int r = 0; r < PPT; ++r) o[r] = b2;
#pragma unroll
    for (int i = 0; i < CH; ++i) {
        const float w = P[144 + i];
#pragma unroll
        for (int r = 0; r < PPT; ++r) o[r] = fmaf(w, h1[i][r], o[r]);
    }

    float4 ov;
    ov.x = o[0]; ov.y = o[1]; ov.z = o[2]; ov.w = o[3];
    *reinterpret_cast<float4*>(out + (size_t)n * HW + p0) = ov;
}

extern "C" void kernel_launch(void* const* d_in, const int* in_sizes, int n_in,
                              void* d_out, int out_size, void* d_ws, size_t ws_size,
                              hipStream_t stream) {
    const float* feats   = (const float*)d_in[0];  // mask_feats [2,8,100,152]
    const float* params  = (const float*)d_in[1];  // mask_head_params [500,169]
    const float* locs    = (const float*)d_in[2];  // instance_locations [500,2]
    const float* soi     = (const float*)d_in[3];  // soi [500]
    const int*   im_inds = (const int*)d_in[4];    // im_inds [500]
    float*       out     = (float*)d_out;          // [500,1,100,152]

    const int quads_per_inst = HW / PPT;                       // 3800
    dim3 block(256);
    dim3 grid((quads_per_inst + block.x - 1) / block.x, NINST); // (15, 500)
    dyn_mask_head<<<grid, block, 0, stream>>>(feats, params, locs, soi, im_inds, out);
}

// Round 2
// 32.067 us; speedup vs baseline: 1.3055x; 1.3055x over previous
//
#include <hip/hip_runtime.h>

#define HGT 100
#define WID 152
#define HW (HGT * WID)          // 15200
#define NINST 500
#define CIN 8
#define CH 8
#define NPARAMS 169
#define PPT 4                    // pixels per thread (one float4)

// param layout per instance (169 floats):
//   w0: [0,80)   (8 x 10)   w1: [80,144) (8 x 8)   w2: [144,152) (1 x 8)
//   b0: [152,160)            b1: [160,168)           b2: [168]

typedef float v4f __attribute__((ext_vector_type(4)));

static __device__ __forceinline__ v4f vsplat(float x) {
    v4f r = {x, x, x, x};
    return r;
}

static __device__ __forceinline__ v4f vfma(v4f a, v4f b, v4f c) {
#if __has_builtin(__builtin_elementwise_fma)
    return __builtin_elementwise_fma(a, b, c);
#else
    return a * b + c;   // -ffp-contract fuses; lowers to v_pk_fma_f32 pairs
#endif
}

static __device__ __forceinline__ v4f vrelu(v4f a) {
#if __has_builtin(__builtin_elementwise_max)
    return __builtin_elementwise_max(a, vsplat(0.0f));
#else
    v4f r;
    r.x = fmaxf(a.x, 0.f); r.y = fmaxf(a.y, 0.f);
    r.z = fmaxf(a.z, 0.f); r.w = fmaxf(a.w, 0.f);
    return r;
#endif
}

__global__ __launch_bounds__(256, 4) void dyn_mask_head(
    const float* __restrict__ feats,   // [2, 8, HW]
    const float* __restrict__ params,  // [500, 169]
    const float* __restrict__ locs,    // [500, 2]
    const float* __restrict__ soi,     // [500]
    const int*  __restrict__ im_inds,  // [500]
    float* __restrict__ out)           // [500, HW]
{
    const int n    = blockIdx.y;                                // instance
    const int quad = blockIdx.x * blockDim.x + threadIdx.x;     // float4 index
    const int p0   = quad * PPT;                                // first pixel
    if (p0 >= HW) return;

    // wave-uniform (blockIdx.y) -> scalar loads into SGPRs
    const int   im      = im_inds[n];
    const float lx      = locs[n * 2 + 0];
    const float ly      = locs[n * 2 + 1];
    const float inv_soi = 1.0f / soi[n];
    const float* __restrict__ P = params + n * NPARAMS;

    // quad lies entirely within one row (WID % 4 == 0)
    const int py  = p0 / WID;
    const int px0 = p0 - py * WID;
    const float rely = (ly - (float)(py * 8 + 4)) * inv_soi;

    v4f relx;
#pragma unroll
    for (int r = 0; r < PPT; ++r)
        relx[r] = (lx - (float)((px0 + r) * 8 + 4)) * inv_soi;

    // load 8 feature channels x 4 pixels as float4 -> v4f
    v4f f[CIN];
    const float* fb = feats + (size_t)im * CIN * HW + p0;
#pragma unroll
    for (int j = 0; j < CIN; ++j) {
        const float4 v = *reinterpret_cast<const float4*>(fb + (size_t)j * HW);
        v4f t = {v.x, v.y, v.z, v.w};
        f[j] = t;
    }

    // ---- layer 0: 10 -> 8, relu ----
    v4f h0[CH];
#pragma unroll
    for (int c = 0; c < CH; ++c) {
        const float s = fmaf(P[c * 10 + 1], rely, P[152 + c]);  // wy*rely + b (scalar)
        v4f acc = vfma(vsplat(P[c * 10 + 0]), relx, vsplat(s)); // + wx*relx
#pragma unroll
        for (int i = 0; i < CIN; ++i)
            acc = vfma(vsplat(P[c * 10 + 2 + i]), f[i], acc);
        h0[c] = vrelu(acc);
    }

    // ---- layer 1: 8 -> 8, relu ----
    v4f h1[CH];
#pragma unroll
    for (int c = 0; c < CH; ++c) {
        v4f acc = vfma(vsplat(P[80 + c * 8]), h0[0], vsplat(P[160 + c]));
#pragma unroll
        for (int i = 1; i < CH; ++i)
            acc = vfma(vsplat(P[80 + c * 8 + i]), h0[i], acc);
        h1[c] = vrelu(acc);
    }

    // ---- layer 2: 8 -> 1 ----
    v4f o = vfma(vsplat(P[144]), h1[0], vsplat(P[168]));
#pragma unroll
    for (int i = 1; i < CH; ++i)
        o = vfma(vsplat(P[144 + i]), h1[i], o);

    float4 ov;
    ov.x = o[0]; ov.y = o[1]; ov.z = o[2]; ov.w = o[3];
    *reinterpret_cast<float4*>(out + (size_t)n * HW + p0) = ov;
}

extern "C" void kernel_launch(void* const* d_in, const int* in_sizes, int n_in,
                              void* d_out, int out_size, void* d_ws, size_t ws_size,
                              hipStream_t stream) {
    const float* feats   = (const float*)d_in[0];  // mask_feats [2,8,100,152]
    const float* params  = (const float*)d_in[1];  // mask_head_params [500,169]
    const float* locs    = (const float*)d_in[2];  // instance_locations [500,2]
    const float* soi     = (const float*)d_in[3];  // soi [500]
    const int*   im_inds = (const int*)d_in[4];    // im_inds [500]
    float*       out     = (float*)d_out;          // [500,1,100,152]

    const int quads_per_inst = HW / PPT;                        // 3800
    dim3 block(256);
    dim3 grid((quads_per_inst + block.x - 1) / block.x, NINST); // (15, 500)
    dyn_mask_head<<<grid, block, 0, stream>>>(feats, params, locs, soi, im_inds, out);
}